// Round 16
// baseline (214.724 us; speedup 1.0000x reference)
//
#include <hip/hip_runtime.h>
#include <hip/hip_bf16.h>
#include <hip/hip_fp8.h>
#include <math.h>

#define BROWS 4096
#define DIM   512
#define YEMB_B 2097152   // 4096*512 bytes, offset of emb rows in Yq (fp8)
#define TSTRIDE 191      // tile stride (tiles are 192 wide, overlap by 1)
#define NT 22            // tiles per dim; triangle blocks = 22*23/2 = 253

typedef float f32x4 __attribute__((ext_vector_type(4)));
typedef int i32x4 __attribute__((ext_vector_type(4)));
typedef int i32x8 __attribute__((ext_vector_type(8)));

// ---------------------------------------------------------------------------
// prep4: wave-per-row, no barriers. 8192 rows (low then emb), 4 rows/block.
// L2-normalize -> fp8 e4m3 row in Yq; s=sum(y^2), r=sum(y) from f32 y.
// (verified R12-R15: absmax 0.0)
// ---------------------------------------------------------------------------
__global__ __launch_bounds__(256) void prep4_kernel(
    const float* __restrict__ low, const float* __restrict__ emb,
    unsigned char* __restrict__ Yq,
    float* __restrict__ s_l, float* __restrict__ r_l,
    float* __restrict__ s_e, float* __restrict__ r_e,
    float* __restrict__ out) {
  const int tid = threadIdx.x;
  const int lane = tid & 63, wid = tid >> 6;
  const int rid = blockIdx.x * 4 + wid;          // 0..8191
  if (blockIdx.x == 0 && tid == 0) out[0] = 0.f;

  const bool is_low = (rid < BROWS);
  const int row = is_low ? rid : rid - BROWS;
  const float* x = (is_low ? low : emb) + (size_t)row * DIM;

  const float4 v0 = ((const float4*)x)[lane * 2];
  const float4 v1 = ((const float4*)x)[lane * 2 + 1];

  float ss = v0.x * v0.x + v0.y * v0.y + v0.z * v0.z + v0.w * v0.w +
             v1.x * v1.x + v1.y * v1.y + v1.z * v1.z + v1.w * v1.w;
#pragma unroll
  for (int o = 1; o < 64; o <<= 1) ss += __shfl_xor(ss, o, 64);
  const float inv = 1.0f / fmaxf(sqrtf(ss), 1e-12f);

  float y[8] = {v0.x * inv, v0.y * inv, v0.z * inv, v0.w * inv,
                v1.x * inv, v1.y * inv, v1.z * inv, v1.w * inv};

  union { unsigned char b[8]; unsigned long long u; } pk;
  float sv = 0.f, rv = 0.f;
#pragma unroll
  for (int i = 0; i < 8; ++i) {
    pk.b[i] = __hip_fp8_e4m3(y[i]).__x;   // OCP e4m3fn, HW RNE
    sv += y[i] * y[i];
    rv += y[i];
  }
  ((unsigned long long*)(Yq + (size_t)rid * 512))[lane] = pk.u;

#pragma unroll
  for (int o = 1; o < 64; o <<= 1) {
    sv += __shfl_xor(sv, o, 64);
    rv += __shfl_xor(rv, o, 64);
  }
  if (lane == 0) {
    (is_low ? s_l : s_e)[row] = sv;
    (is_low ? r_l : r_e)[row] = rv;
  }
}

// ---------------------------------------------------------------------------
// Symmetric fused MFMA kernel, round 16: R15 geometry + MX-scaled MFMA.
// ONE change vs R15 (45.4 us, no spill, zero tail): the K-loop uses
// v_mfma_scale_f32_16x16x128_f8f6f4 (fmt fp8/fp8, unit E8M0 scales=127)
// - K=128 per instruction: per round 18 MFMA + 72 b128 reads per wave
//   (vs 144 MFMA + 144 b64) -> MFMA pipe ~21k -> ~4.3k cyc/SIMD,
//   instruction issue collapses ~6x.
// A/B layout: lane holds 32 B = k=quad*32..+31 (family pattern, K/4 per
//   quad) = chunks {2q, 2q+1} of our swizzled 128 B rows. C/D layout
//   shape-determined (m121-128) -> epilogue unchanged.
// Grid 253 blocks (192x192 tiles, stride 191), 1 block/CU (LDS 106 KB),
// 8 waves 4x2, wave tile 48x96, acc 144 AGPR under the (512,2) 256 cap.
// Staging/swizzle byte-identical to R15 (chunk p holds global p^(rloc&7)).
// ---------------------------------------------------------------------------
__global__ __launch_bounds__(512, 2) void fused_sym_kernel(
    const unsigned char* __restrict__ Yq,
    const float* __restrict__ s_l, const float* __restrict__ r_l,
    const float* __restrict__ s_e, const float* __restrict__ r_e,
    float* __restrict__ out) {
  __shared__ __align__(16) unsigned char lds8[98304];  // 96 KB staging
  __shared__ float hand_d[4][48][2];    // dl/de at tile col 96, per wr
  __shared__ float hand_t[4][192][2];   // dl/de at tile row 48*wr ([wr-1])
  __shared__ float sred[8];

  // decode upper-triangle block id
  int rem = blockIdx.x, br = 0;
  while (rem >= NT - br) { rem -= NT - br; ++br; }
  const int bc = br + rem;
  const bool diag = (br == bc);

  const int tid = threadIdx.x;
  const int lane = tid & 63;
  const int wid = tid >> 6;          // 0..7
  const int wr = wid >> 1;           // 0..3: rows 48*wr..48*wr+47
  const int wc = wid & 1;            // 0..1: cols 96*wc..96*wc+95
  const int quad = lane >> 4, cpos = lane & 15;
  const int sw = cpos & 7;
  const int r0 = br * TSTRIDE, c0 = bc * TSTRIDE;

  // staging: 6144 slots of 16B (4 segs x 192 rows x 8 chunks);
  // thread owns slot c = tid + 512*s, s=0..11.
  // slot chunk p = c&7 holds GLOBAL chunk p ^ (rloc&7)  [swizzle].
  int goff[12];   // BYTE offsets into Yq (add k0 = it*128 per round)
#pragma unroll
  for (int s = 0; s < 12; ++s) {
    const int c = tid + 512 * s;
    const int seg = c / 1536;
    const int rloc = (c % 1536) >> 3;
    int base;
    if (seg == 0)      base = min(r0 + rloc, BROWS - 1) * 512;
    else if (seg == 1) base = YEMB_B + min(r0 + rloc, BROWS - 1) * 512;
    else if (seg == 2) base = min(c0 + rloc, BROWS - 1) * 512;
    else               base = YEMB_B + min(c0 + rloc, BROWS - 1) * 512;
    goff[s] = base + (((c & 7) ^ (rloc & 7)) << 4);
  }

  // frag base byte offsets (seg bytes: Alow 0, Aemb 24576, Blow 49152,
  // Bemb 73728; row stride 128 B; u/v stride 16 rows = 2048 B)
  const int abase_l = (48 * wr + cpos) * 128;
  const int abase_e = 24576 + (48 * wr + cpos) * 128;
  const int bbase_l = (diag ? 0 : 49152) + (96 * wc + cpos) * 128;
  const int bbase_e = (diag ? 24576 : 73728) + (96 * wc + cpos) * 128;

  // the two swizzled 16B-chunk offsets this lane's quad needs (k=quad*32..)
  const int ch0 = ((2 * quad + 0) ^ sw) << 4;
  const int ch1 = ((2 * quad + 1) ^ sw) << 4;

  f32x4 accl[3][6], acce[3][6];
#pragma unroll
  for (int u = 0; u < 3; ++u)
#pragma unroll
    for (int v = 0; v < 6; ++v) {
      accl[u][v] = (f32x4)(0.f);
      acce[u][v] = (f32x4)(0.f);
    }

  for (int it = 0; it < 4; ++it) {
    const int k0 = it * 128;
#pragma unroll
    for (int s = 0; s < 12; ++s) {
      if (s < 6 || !diag)   // slots >= 3072 are B segments; skip when diag
        __builtin_amdgcn_global_load_lds(
            (const __attribute__((address_space(1))) void*)(Yq + goff[s] + k0),
            (__attribute__((address_space(3))) void*)(lds8 + (tid + 512 * s) * 16),
            16, 0, 0);
    }
    __syncthreads();

    {  // low matrix: K=128 in one MFMA per (u,v)
      i32x8 a[3], b[6];
#pragma unroll
      for (int u = 0; u < 3; ++u) {
        const i32x4 lo = *(const i32x4*)(lds8 + abase_l + u * 2048 + ch0);
        const i32x4 hi = *(const i32x4*)(lds8 + abase_l + u * 2048 + ch1);
        a[u][0] = lo[0]; a[u][1] = lo[1]; a[u][2] = lo[2]; a[u][3] = lo[3];
        a[u][4] = hi[0]; a[u][5] = hi[1]; a[u][6] = hi[2]; a[u][7] = hi[3];
      }
#pragma unroll
      for (int v = 0; v < 6; ++v) {
        const i32x4 lo = *(const i32x4*)(lds8 + bbase_l + v * 2048 + ch0);
        const i32x4 hi = *(const i32x4*)(lds8 + bbase_l + v * 2048 + ch1);
        b[v][0] = lo[0]; b[v][1] = lo[1]; b[v][2] = lo[2]; b[v][3] = lo[3];
        b[v][4] = hi[0]; b[v][5] = hi[1]; b[v][6] = hi[2]; b[v][7] = hi[3];
      }
#pragma unroll
      for (int u = 0; u < 3; ++u)
#pragma unroll
        for (int v = 0; v < 6; ++v)
          accl[u][v] = __builtin_amdgcn_mfma_scale_f32_16x16x128_f8f6f4(
              a[u], b[v], accl[u][v], 0, 0,   // cbsz=0 (fp8), blgp=0 (fp8)
              0, 127,                         // scale_a: opsel 0, E8M0 127 = 1.0
              0, 127);                        // scale_b: opsel 0, E8M0 127 = 1.0
    }
    {  // emb matrix
      i32x8 a[3], b[6];
#pragma unroll
      for (int u = 0; u < 3; ++u) {
        const i32x4 lo = *(const i32x4*)(lds8 + abase_e + u * 2048 + ch0);
        const i32x4 hi = *(const i32x4*)(lds8 + abase_e + u * 2048 + ch1);
        a[u][0] = lo[0]; a[u][1] = lo[1]; a[u][2] = lo[2]; a[u][3] = lo[3];
        a[u][4] = hi[0]; a[u][5] = hi[1]; a[u][6] = hi[2]; a[u][7] = hi[3];
      }
#pragma unroll
      for (int v = 0; v < 6; ++v) {
        const i32x4 lo = *(const i32x4*)(lds8 + bbase_e + v * 2048 + ch0);
        const i32x4 hi = *(const i32x4*)(lds8 + bbase_e + v * 2048 + ch1);
        b[v][0] = lo[0]; b[v][1] = lo[1]; b[v][2] = lo[2]; b[v][3] = lo[3];
        b[v][4] = hi[0]; b[v][5] = hi[1]; b[v][6] = hi[2]; b[v][7] = hi[3];
      }
#pragma unroll
      for (int u = 0; u < 3; ++u)
#pragma unroll
        for (int v = 0; v < 6; ++v)
          acce[u][v] = __builtin_amdgcn_mfma_scale_f32_16x16x128_f8f6f4(
              a[u], b[v], acce[u][v], 0, 0, 0, 127, 0, 127);
    }
    __syncthreads();
  }

  // ---- transform both accs -> distances in place ----
  const float epst = (float)DIM * 1e-6f * 1e-6f;
#pragma unroll
  for (int v = 0; v < 6; ++v) {
    const int j = min(c0 + 96 * wc + 16 * v + cpos, BROWS - 1);
    const float sjl = s_l[j], rjl = r_l[j];
    const float sje = s_e[j], rje = r_e[j];
#pragma unroll
    for (int u = 0; u < 3; ++u)
#pragma unroll
      for (int r = 0; r < 4; ++r) {
        const int i = min(r0 + 48 * wr + 16 * u + 4 * quad + r, BROWS - 1);
        const float sql = s_l[i] + sjl - 2.f * accl[u][v][r] +
                          2e-6f * (r_l[i] - rjl) + epst;
        accl[u][v][r] = sqrtf(fmaxf(sql, 0.f));
        const float sqe = s_e[i] + sje - 2.f * acce[u][v][r] +
                          2e-6f * (r_e[i] - rje) + epst;
        acce[u][v][r] = sqrtf(fmaxf(sqe, 0.f));
      }
  }
  // now: dl in accl, de in acce

  // ---- publish cross-wave boundary values (dl and de) ----
  if (wc == 1 && cpos == 0) {   // tile col 96 for this wr's 48 rows
#pragma unroll
    for (int u = 0; u < 3; ++u)
#pragma unroll
      for (int r = 0; r < 4; ++r) {
        hand_d[wr][16 * u + 4 * quad + r][0] = accl[u][0][r];
        hand_d[wr][16 * u + 4 * quad + r][1] = acce[u][0][r];
      }
  }
  if (quad == 0 && wr >= 1) {   // tile row 48*wr (u=0,r=0) for 96 cols
#pragma unroll
    for (int v = 0; v < 6; ++v) {
      hand_t[wr - 1][96 * wc + 16 * v + cpos][0] = accl[0][v][0];
      hand_t[wr - 1][96 * wc + 16 * v + cpos][1] = acce[0][v][0];
    }
  }
  __syncthreads();

  float sum = 0.f;

  // ---- pass 1: direct terms (i in rows, pair cols j,j+1) ----
  const int srcin = (lane & 48) | ((cpos + 1) & 15);
#pragma unroll
  for (int u = 0; u < 3; ++u)
#pragma unroll
    for (int r = 0; r < 4; ++r) {
      const int trow = 48 * wr + 16 * u + 4 * quad + r;
      const int i = r0 + trow;
      const bool rowok = (trow <= TSTRIDE - 1) && (i <= BROWS - 2);
#pragma unroll
      for (int v = 0; v < 6; ++v) {
        const float dl1 = accl[u][v][r], de1 = acce[u][v][r];
        float dl2 = __shfl(dl1, srcin, 64);
        float de2 = __shfl(de1, srcin, 64);
        if (v < 5) {
          const float dlb = __shfl(accl[u][v + 1][r], lane & 48, 64);
          const float deb = __shfl(acce[u][v + 1][r], lane & 48, 64);
          if (cpos == 15) { dl2 = dlb; de2 = deb; }
        } else if (cpos == 15 && wc == 0) {
          dl2 = hand_d[wr][16 * u + 4 * quad + r][0];
          de2 = hand_d[wr][16 * u + 4 * quad + r][1];
        }
        const int tcol = 96 * wc + 16 * v + cpos;
        const int j = c0 + tcol;
        if (rowok && tcol <= TSTRIDE - 1 && j <= BROWS - 3) {
          const float aa = dl1 - dl2, bb = de1 - de2;
          const float coeff = (float)((aa > 0.f) - (aa < 0.f)) -
                              (float)((bb > 0.f) - (bb < 0.f));
          sum += coeff * (de2 - de1);
        }
      }
    }

  // ---- pass 2: transposed terms (i in cols, pair rows j,j+1), off-diag only ----
  if (!diag) {
#pragma unroll
    for (int u = 0; u < 3; ++u)
#pragma unroll
      for (int v = 0; v < 6; ++v) {
        const int tcol = 96 * wc + 16 * v + cpos;
        const int ii = c0 + tcol;
        const bool colok = (tcol <= TSTRIDE - 1) && (ii <= BROWS - 2);
#pragma unroll
        for (int r = 0; r < 4; ++r) {
          const int trow = 48 * wr + 16 * u + 4 * quad + r;
          const int jj = r0 + trow;
          float dl2, de2;
          if (r < 3) {
            dl2 = accl[u][v][r + 1];
            de2 = acce[u][v][r + 1];
          } else {
            const float dlq = __shfl(accl[u][v][0], (lane + 16) & 63, 64);
            const float deq = __shfl(acce[u][v][0], (lane + 16) & 63, 64);
            const int un = (u < 2) ? u + 1 : u;
            const float dlu = __shfl(accl[un][v][0], cpos, 64);
            const float deu = __shfl(acce[un][v][0], cpos, 64);
            if (quad < 3)    { dl2 = dlq; de2 = deq; }
            else if (u < 2)  { dl2 = dlu; de2 = deu; }
            else             { dl2 = hand_t[wr][tcol][0];   // wr==3 filtered
                               de2 = hand_t[wr][tcol][1]; }
          }
          if (colok && trow <= TSTRIDE - 1 && jj <= BROWS - 3) {
            const float dl1 = accl[u][v][r], de1 = acce[u][v][r];
            const float aa = dl1 - dl2, bb = de1 - de2;
            const float coeff = (float)((aa > 0.f) - (aa < 0.f)) -
                                (float)((bb > 0.f) - (bb < 0.f));
            sum += coeff * (de2 - de1);
          }
        }
      }
  }

  // ---- reduce + atomic ----
#pragma unroll
  for (int o = 32; o; o >>= 1) sum += __shfl_down(sum, o, 64);
  if (lane == 0) sred[wid] = sum;
  __syncthreads();
  if (tid == 0) {
    const float scale = 1.0f / ((float)(BROWS - 1) * (float)(BROWS - 2));
    float t = 0.f;
#pragma unroll
    for (int w = 0; w < 8; ++w) t += sred[w];
    atomicAdd(out, t * scale);
  }
}

// ===========================================================================
extern "C" void kernel_launch(void* const* d_in, const int* in_sizes, int n_in,
                              void* d_out, int out_size, void* d_ws,
                              size_t ws_size, hipStream_t stream) {
  const float* low = (const float*)d_in[0];
  const float* emb = (const float*)d_in[1];
  float* out = (float*)d_out;

  // ws: Yq (2*4096*512 fp8 = 4 MB) then s_l, r_l, s_e, r_e (4096 f32 each)
  unsigned char* Yq = (unsigned char*)d_ws;
  float* s_l = (float*)(Yq + 2 * (size_t)BROWS * DIM);
  float* r_l = s_l + BROWS;
  float* s_e = r_l + BROWS;
  float* r_e = s_e + BROWS;

  prep4_kernel<<<2 * BROWS / 4, 256, 0, stream>>>(low, emb, Yq, s_l, r_l, s_e, r_e, out);
  fused_sym_kernel<<<NT * (NT + 1) / 2, 512, 0, stream>>>(Yq, s_l, r_l, s_e, r_e, out);
}

// Round 17
// 108.021 us; speedup vs baseline: 1.9878x; 1.9878x over previous
//
#include <hip/hip_runtime.h>
#include <hip/hip_bf16.h>
#include <hip/hip_fp8.h>
#include <math.h>

#define BROWS 4096
#define DIM   512
#define YEMB_B 2097152   // 4096*512 bytes, offset of emb rows in Yq (fp8)
#define TSTRIDE 191      // tile stride (tiles are 192 wide, overlap by 1)
#define NT 22            // tiles per dim; triangle blocks = 22*23/2 = 253

typedef float f32x4 __attribute__((ext_vector_type(4)));

// ---------------------------------------------------------------------------
// prep4: wave-per-row, no barriers. 8192 rows (low then emb), 4 rows/block.
// L2-normalize -> fp8 e4m3 row in Yq; s=sum(y^2), r=sum(y) from f32 y.
// (verified R12-R15: absmax 0.0)
// ---------------------------------------------------------------------------
__global__ __launch_bounds__(256) void prep4_kernel(
    const float* __restrict__ low, const float* __restrict__ emb,
    unsigned char* __restrict__ Yq,
    float* __restrict__ s_l, float* __restrict__ r_l,
    float* __restrict__ s_e, float* __restrict__ r_e,
    float* __restrict__ out) {
  const int tid = threadIdx.x;
  const int lane = tid & 63, wid = tid >> 6;
  const int rid = blockIdx.x * 4 + wid;          // 0..8191
  if (blockIdx.x == 0 && tid == 0) out[0] = 0.f;

  const bool is_low = (rid < BROWS);
  const int row = is_low ? rid : rid - BROWS;
  const float* x = (is_low ? low : emb) + (size_t)row * DIM;

  const float4 v0 = ((const float4*)x)[lane * 2];
  const float4 v1 = ((const float4*)x)[lane * 2 + 1];

  float ss = v0.x * v0.x + v0.y * v0.y + v0.z * v0.z + v0.w * v0.w +
             v1.x * v1.x + v1.y * v1.y + v1.z * v1.z + v1.w * v1.w;
#pragma unroll
  for (int o = 1; o < 64; o <<= 1) ss += __shfl_xor(ss, o, 64);
  const float inv = 1.0f / fmaxf(sqrtf(ss), 1e-12f);

  float y[8] = {v0.x * inv, v0.y * inv, v0.z * inv, v0.w * inv,
                v1.x * inv, v1.y * inv, v1.z * inv, v1.w * inv};

  union { unsigned char b[8]; unsigned long long u; } pk;
  float sv = 0.f, rv = 0.f;
#pragma unroll
  for (int i = 0; i < 8; ++i) {
    pk.b[i] = __hip_fp8_e4m3(y[i]).__x;   // OCP e4m3fn, HW RNE
    sv += y[i] * y[i];
    rv += y[i];
  }
  ((unsigned long long*)(Yq + (size_t)rid * 512))[lane] = pk.u;

#pragma unroll
  for (int o = 1; o < 64; o <<= 1) {
    sv += __shfl_xor(sv, o, 64);
    rv += __shfl_xor(rv, o, 64);
  }
  if (lane == 0) {
    (is_low ? s_l : s_e)[row] = sv;
    (is_low ? r_l : r_e)[row] = rv;
  }
}

// ---------------------------------------------------------------------------
// Symmetric fused MFMA kernel, round 17 = exact revert to R15 (verified
// best: fused 45.4 us, no spill, zero tail). R16's K=128 scaled MFMA
// spilled catastrophically (72 live operand VGPRs + 144 AGPR acc > cap).
// Geometry: 192x192 tiles (stride 191), NT=22 -> 253 blocks; LDS 106 KB
// forces exactly 1 block/CU -> all blocks co-resident, zero tail.
// Block: 512 thr, 8 waves 4x2 (wr rows 48*wr.., wc cols 96*wc..), wave
// tile 48x96 per matrix, acc 144 AGPR under the (512,2) 256-reg cap.
// K-loop: BK=128 fp8, 4 rounds, 96 KB/round staging via global_load_lds
// w=16; slot chunk p holds global chunk p ^ (rloc&7) (swizzle); frag-side
// term sw = cpos&7. MFMA: f32_16x16x32_fp8_fp8 (i64 ops).
// C/D: col=lane&15, row=(lane>>4)*4+reg (m89/m91, shape-determined).
// Epilogue: direct + transposed (symmetry) pair terms, shfl + LDS hands.
// ---------------------------------------------------------------------------
__global__ __launch_bounds__(512, 2) void fused_sym_kernel(
    const unsigned char* __restrict__ Yq,
    const float* __restrict__ s_l, const float* __restrict__ r_l,
    const float* __restrict__ s_e, const float* __restrict__ r_e,
    float* __restrict__ out) {
  __shared__ __align__(16) unsigned char lds8[98304];  // 96 KB staging
  __shared__ float hand_d[4][48][2];    // dl/de at tile col 96, per wr
  __shared__ float hand_t[4][192][2];   // dl/de at tile row 48*wr ([wr-1])
  __shared__ float sred[8];

  // decode upper-triangle block id
  int rem = blockIdx.x, br = 0;
  while (rem >= NT - br) { rem -= NT - br; ++br; }
  const int bc = br + rem;
  const bool diag = (br == bc);

  const int tid = threadIdx.x;
  const int lane = tid & 63;
  const int wid = tid >> 6;          // 0..7
  const int wr = wid >> 1;           // 0..3: rows 48*wr..48*wr+47
  const int wc = wid & 1;            // 0..1: cols 96*wc..96*wc+95
  const int quad = lane >> 4, cpos = lane & 15;
  const int sw = cpos & 7;
  const int r0 = br * TSTRIDE, c0 = bc * TSTRIDE;

  // staging: 6144 slots of 16B (4 segs x 192 rows x 8 chunks);
  // thread owns slot c = tid + 512*s, s=0..11.
  // segs (slots): [0,1536) A_low, [1536,3072) A_emb,
  //               [3072,4608) B_low, [4608,6144) B_emb.
  // slot chunk p = c&7 holds GLOBAL chunk p ^ (rloc&7)  [swizzle].
  int goff[12];   // BYTE offsets into Yq (add k0 = it*128 per round)
#pragma unroll
  for (int s = 0; s < 12; ++s) {
    const int c = tid + 512 * s;
    const int seg = c / 1536;
    const int rloc = (c % 1536) >> 3;
    int base;
    if (seg == 0)      base = min(r0 + rloc, BROWS - 1) * 512;
    else if (seg == 1) base = YEMB_B + min(r0 + rloc, BROWS - 1) * 512;
    else if (seg == 2) base = min(c0 + rloc, BROWS - 1) * 512;
    else               base = YEMB_B + min(c0 + rloc, BROWS - 1) * 512;
    goff[s] = base + (((c & 7) ^ (rloc & 7)) << 4);
  }

  // frag base byte offsets (seg bytes: Alow 0, Aemb 24576, Blow 49152,
  // Bemb 73728; row stride 128 B; u/v stride 16 rows = 2048 B)
  const int abase_l = (48 * wr + cpos) * 128;
  const int abase_e = 24576 + (48 * wr + cpos) * 128;
  const int bbase_l = (diag ? 0 : 49152) + (96 * wc + cpos) * 128;
  const int bbase_e = (diag ? 24576 : 73728) + (96 * wc + cpos) * 128;

  f32x4 accl[3][6], acce[3][6];
#pragma unroll
  for (int u = 0; u < 3; ++u)
#pragma unroll
    for (int v = 0; v < 6; ++v) {
      accl[u][v] = (f32x4)(0.f);
      acce[u][v] = (f32x4)(0.f);
    }

  for (int it = 0; it < 4; ++it) {
    const int k0 = it * 128;
#pragma unroll
    for (int s = 0; s < 12; ++s) {
      if (s < 6 || !diag)   // slots >= 3072 are B segments; skip when diag
        __builtin_amdgcn_global_load_lds(
            (const __attribute__((address_space(1))) void*)(Yq + goff[s] + k0),
            (__attribute__((address_space(3))) void*)(lds8 + (tid + 512 * s) * 16),
            16, 0, 0);
    }
    __syncthreads();

#pragma unroll
    for (int kk = 0; kk < 4; ++kk) {
      const int ch = (((2 * kk + (quad >> 1)) ^ sw) << 4) + (quad & 1) * 8;
      {  // low matrix
        long a[3], b[6];
#pragma unroll
        for (int u = 0; u < 3; ++u) a[u] = *(const long*)(lds8 + abase_l + u * 2048 + ch);
#pragma unroll
        for (int v = 0; v < 6; ++v) b[v] = *(const long*)(lds8 + bbase_l + v * 2048 + ch);
#pragma unroll
        for (int u = 0; u < 3; ++u)
#pragma unroll
          for (int v = 0; v < 6; ++v)
            accl[u][v] = __builtin_amdgcn_mfma_f32_16x16x32_fp8_fp8(
                a[u], b[v], accl[u][v], 0, 0, 0);
      }
      {  // emb matrix
        long a[3], b[6];
#pragma unroll
        for (int u = 0; u < 3; ++u) a[u] = *(const long*)(lds8 + abase_e + u * 2048 + ch);
#pragma unroll
        for (int v = 0; v < 6; ++v) b[v] = *(const long*)(lds8 + bbase_e + v * 2048 + ch);
#pragma unroll
        for (int u = 0; u < 3; ++u)
#pragma unroll
          for (int v = 0; v < 6; ++v)
            acce[u][v] = __builtin_amdgcn_mfma_f32_16x16x32_fp8_fp8(
                a[u], b[v], acce[u][v], 0, 0, 0);
      }
    }
    __syncthreads();
  }

  // ---- transform both accs -> distances in place ----
  const float epst = (float)DIM * 1e-6f * 1e-6f;
#pragma unroll
  for (int v = 0; v < 6; ++v) {
    const int j = min(c0 + 96 * wc + 16 * v + cpos, BROWS - 1);
    const float sjl = s_l[j], rjl = r_l[j];
    const float sje = s_e[j], rje = r_e[j];
#pragma unroll
    for (int u = 0; u < 3; ++u)
#pragma unroll
      for (int r = 0; r < 4; ++r) {
        const int i = min(r0 + 48 * wr + 16 * u + 4 * quad + r, BROWS - 1);
        const float sql = s_l[i] + sjl - 2.f * accl[u][v][r] +
                          2e-6f * (r_l[i] - rjl) + epst;
        accl[u][v][r] = sqrtf(fmaxf(sql, 0.f));
        const float sqe = s_e[i] + sje - 2.f * acce[u][v][r] +
                          2e-6f * (r_e[i] - rje) + epst;
        acce[u][v][r] = sqrtf(fmaxf(sqe, 0.f));
      }
  }
  // now: dl in accl, de in acce

  // ---- publish cross-wave boundary values (dl and de) ----
  if (wc == 1 && cpos == 0) {   // tile col 96 for this wr's 48 rows
#pragma unroll
    for (int u = 0; u < 3; ++u)
#pragma unroll
      for (int r = 0; r < 4; ++r) {
        hand_d[wr][16 * u + 4 * quad + r][0] = accl[u][0][r];
        hand_d[wr][16 * u + 4 * quad + r][1] = acce[u][0][r];
      }
  }
  if (quad == 0 && wr >= 1) {   // tile row 48*wr (u=0,r=0) for 96 cols
#pragma unroll
    for (int v = 0; v < 6; ++v) {
      hand_t[wr - 1][96 * wc + 16 * v + cpos][0] = accl[0][v][0];
      hand_t[wr - 1][96 * wc + 16 * v + cpos][1] = acce[0][v][0];
    }
  }
  __syncthreads();

  float sum = 0.f;

  // ---- pass 1: direct terms (i in rows, pair cols j,j+1) ----
  const int srcin = (lane & 48) | ((cpos + 1) & 15);
#pragma unroll
  for (int u = 0; u < 3; ++u)
#pragma unroll
    for (int r = 0; r < 4; ++r) {
      const int trow = 48 * wr + 16 * u + 4 * quad + r;
      const int i = r0 + trow;
      const bool rowok = (trow <= TSTRIDE - 1) && (i <= BROWS - 2);
#pragma unroll
      for (int v = 0; v < 6; ++v) {
        const float dl1 = accl[u][v][r], de1 = acce[u][v][r];
        float dl2 = __shfl(dl1, srcin, 64);
        float de2 = __shfl(de1, srcin, 64);
        if (v < 5) {
          const float dlb = __shfl(accl[u][v + 1][r], lane & 48, 64);
          const float deb = __shfl(acce[u][v + 1][r], lane & 48, 64);
          if (cpos == 15) { dl2 = dlb; de2 = deb; }
        } else if (cpos == 15 && wc == 0) {
          dl2 = hand_d[wr][16 * u + 4 * quad + r][0];
          de2 = hand_d[wr][16 * u + 4 * quad + r][1];
        }
        const int tcol = 96 * wc + 16 * v + cpos;
        const int j = c0 + tcol;
        if (rowok && tcol <= TSTRIDE - 1 && j <= BROWS - 3) {
          const float aa = dl1 - dl2, bb = de1 - de2;
          const float coeff = (float)((aa > 0.f) - (aa < 0.f)) -
                              (float)((bb > 0.f) - (bb < 0.f));
          sum += coeff * (de2 - de1);
        }
      }
    }

  // ---- pass 2: transposed terms (i in cols, pair rows j,j+1), off-diag only ----
  if (!diag) {
#pragma unroll
    for (int u = 0; u < 3; ++u)
#pragma unroll
      for (int v = 0; v < 6; ++v) {
        const int tcol = 96 * wc + 16 * v + cpos;
        const int ii = c0 + tcol;
        const bool colok = (tcol <= TSTRIDE - 1) && (ii <= BROWS - 2);
#pragma unroll
        for (int r = 0; r < 4; ++r) {
          const int trow = 48 * wr + 16 * u + 4 * quad + r;
          const int jj = r0 + trow;
          float dl2, de2;
          if (r < 3) {
            dl2 = accl[u][v][r + 1];
            de2 = acce[u][v][r + 1];
          } else {
            const float dlq = __shfl(accl[u][v][0], (lane + 16) & 63, 64);
            const float deq = __shfl(acce[u][v][0], (lane + 16) & 63, 64);
            const int un = (u < 2) ? u + 1 : u;
            const float dlu = __shfl(accl[un][v][0], cpos, 64);
            const float deu = __shfl(acce[un][v][0], cpos, 64);
            if (quad < 3)    { dl2 = dlq; de2 = deq; }
            else if (u < 2)  { dl2 = dlu; de2 = deu; }
            else             { dl2 = hand_t[wr][tcol][0];   // wr==3 filtered
                               de2 = hand_t[wr][tcol][1]; }
          }
          if (colok && trow <= TSTRIDE - 1 && jj <= BROWS - 3) {
            const float dl1 = accl[u][v][r], de1 = acce[u][v][r];
            const float aa = dl1 - dl2, bb = de1 - de2;
            const float coeff = (float)((aa > 0.f) - (aa < 0.f)) -
                                (float)((bb > 0.f) - (bb < 0.f));
            sum += coeff * (de2 - de1);
          }
        }
      }
  }

  // ---- reduce + atomic ----
#pragma unroll
  for (int o = 32; o; o >>= 1) sum += __shfl_down(sum, o, 64);
  if (lane == 0) sred[wid] = sum;
  __syncthreads();
  if (tid == 0) {
    const float scale = 1.0f / ((float)(BROWS - 1) * (float)(BROWS - 2));
    float t = 0.f;
#pragma unroll
    for (int w = 0; w < 8; ++w) t += sred[w];
    atomicAdd(out, t * scale);
  }
}

// ===========================================================================
extern "C" void kernel_launch(void* const* d_in, const int* in_sizes, int n_in,
                              void* d_out, int out_size, void* d_ws,
                              size_t ws_size, hipStream_t stream) {
  const float* low = (const float*)d_in[0];
  const float* emb = (const float*)d_in[1];
  float* out = (float*)d_out;

  // ws: Yq (2*4096*512 fp8 = 4 MB) then s_l, r_l, s_e, r_e (4096 f32 each)
  unsigned char* Yq = (unsigned char*)d_ws;
  float* s_l = (float*)(Yq + 2 * (size_t)BROWS * DIM);
  float* r_l = s_l + BROWS;
  float* s_e = r_l + BROWS;
  float* r_e = s_e + BROWS;

  prep4_kernel<<<2 * BROWS / 4, 256, 0, stream>>>(low, emb, Yq, s_l, r_l, s_e, r_e, out);
  fused_sym_kernel<<<NT * (NT + 1) / 2, 512, 0, stream>>>(Yq, s_l, r_l, s_e, r_e, out);
}